// Round 7
// baseline (407.783 us; speedup 1.0000x reference)
//
#include <hip/hip_runtime.h>
#include <math.h>

#define NPART 32768
#define MS 50
#define BLOCK 256

typedef __attribute__((ext_vector_type(8))) short bfrag;   // 8 bf16 (4 VGPRs)
typedef __attribute__((ext_vector_type(4))) float ffrag;   // 4 fp32 (MFMA C/D)

// float -> bf16 bits, round-to-nearest-even (staging / fallback)
__device__ __forceinline__ unsigned short f2bf(float x) {
    unsigned u = __float_as_uint(x);
    u += 0x7fffu + ((u >> 16) & 1u);
    return (unsigned short)(u >> 16);
}

#if __has_builtin(__builtin_amdgcn_cvt_pk_bf16_f32)
typedef __attribute__((ext_vector_type(2))) __bf16 bf16x2;
__device__ __forceinline__ unsigned pk2(float a, float b) {
    bf16x2 r = __builtin_amdgcn_cvt_pk_bf16_f32(a, b);   // lo=a, hi=b
    return __builtin_bit_cast(unsigned, r);
}
#else
__device__ __forceinline__ unsigned pk2(float a, float b) {
    return (unsigned)f2bf(a) | ((unsigned)f2bf(b) << 16);
}
#endif

// tanh(x) = 1 - 2/(exp(2x)+1); saturates correctly at +/-inf.
__device__ __forceinline__ float fast_tanh(float x) {
    float e = __expf(2.0f * x);
    return 1.0f - __fdividef(2.0f, e + 1.0f);
}

// ZERO-LDS main loop. One wave = 16 particles (p = lane&15, q = lane>>4).
// X state lives in GEMM2's D-layout: lane(p,q) owns X dims {4q+r, 16+4q+r}
// (r=0..3) of particle p.
//
// GEMM1: H(128x16) = W1x^T @ X.  B-operand = packed X regs; the k-slot (q,j)
//   carries feature delta(q,j) = 4q+(j&3)+16(j>>2), and W1's A-fragments are
//   loaded delta-permuted so the contraction is exact. C/D: lane(p,q) reg r
//   of tile mt = H[16mt+4q+r][particle p]. C-init = static-feature fold
//   (b1 + Y.W1y + t*W1t + s*W1s), fp32, 1 fma/row/step.
//
// GEMM2: Z(32x16) = W2^T @ H. The tanh'd GEMM1 C-regs ARE the B-operand:
//   B-slot (kt,q,j) carries hidden kappa(kt,q,j) = 32kt+16(j>>2)+4q+(j&3)
//   = C-reg (mt=2kt+(j>>2), r=j&3); W2^T A-fragments are kappa-permuted.
//   D: lane(p,q) reg r of tile nt = Z[16nt+4q+r][particle p] — exactly the
//   X layout. X/V updates run fully in-register; no LDS round trip at all.
__global__ __launch_bounds__(BLOCK, 2)
void fused_sde_mfma(const float* __restrict__ obs,
                    const float* __restrict__ x0,
                    const float* __restrict__ v0,
                    const float* __restrict__ noise,
                    const float* __restrict__ gW1,
                    const float* __restrict__ gb1,
                    const float* __restrict__ gW2,
                    const float* __restrict__ gb2,
                    const float* __restrict__ gtheta,
                    const int* __restrict__ gobs_idx,
                    const int* __restrict__ gctrl,
                    float* __restrict__ outX,
                    float* __restrict__ outV)
{
    const int tid  = threadIdx.x;
    const int w    = tid >> 6;
    const int lane = tid & 63;
    const int p    = lane & 15;
    const int q    = lane >> 4;
    const int part = blockIdx.x * 64 + w * 16 + p;

    const float theta = gtheta[0];
    const float tfeat = (float)gobs_idx[0];
    const float cr    = (float)gctrl[0];
    const float dt      = 1.0f / (float)MS;
    const float sqrt_dt = sqrtf(dt);
    const float ax  = 1.0f - dt * theta;
    const float bcr = dt * cr;
    const float kv  = dt * (0.5f - cr);

    // ---- GEMM1 A-fragments: W1 X-block, feature delta-permuted ----
    bfrag A1[8];
    #pragma unroll
    for (int mt = 0; mt < 8; ++mt) {
        const int h = 16 * mt + p;
        bfrag a;
        #pragma unroll
        for (int j = 0; j < 8; ++j) {
            const int f = 4 * q + (j & 3) + 16 * (j >> 2);   // delta(q,j)
            a[j] = (short)f2bf(gW1[f * 128 + h]);
        }
        A1[mt] = a;
    }

    // ---- GEMM2 A-fragments: W2^T, hidden kappa-permuted ----
    bfrag A2[2][4];
    #pragma unroll
    for (int nt = 0; nt < 2; ++nt) {
        #pragma unroll
        for (int kt = 0; kt < 4; ++kt) {
            bfrag a;
            #pragma unroll
            for (int j = 0; j < 8; ++j) {
                const int h = 32 * kt + 16 * (j >> 2) + 4 * q + (j & 3);  // kappa
                a[j] = (short)f2bf(gW2[h * 32 + 16 * nt + p]);
            }
            A2[nt][kt] = a;
        }
    }

    // ---- static C-init for GEMM1 (rows 16mt+4q+r) ----
    ffrag Stat[8], W1s[8];
    #pragma unroll
    for (int mt = 0; mt < 8; ++mt) {
        #pragma unroll
        for (int r = 0; r < 4; ++r) {
            const int h = 16 * mt + 4 * q + r;
            float acc = gb1[h];
            #pragma unroll
            for (int j = 0; j < 8; ++j)
                acc = fmaf(obs[j], gW1[(32 + j) * 128 + h], acc);
            acc = fmaf(tfeat, gW1[41 * 128 + h], acc);
            Stat[mt][r] = acc;
            W1s[mt][r]  = gW1[40 * 128 + h];
        }
    }

    // GEMM2 C-init from b2: rows 16nt+4q+r.
    ffrag Z0i, Z1i;
    {
        float4 b = *(const float4*)(gb2 + 4 * q);
        Z0i = ffrag{b.x, b.y, b.z, b.w};
        float4 c = *(const float4*)(gb2 + 16 + 4 * q);
        Z1i = ffrag{c.x, c.y, c.z, c.w};
    }
    const ffrag Zzero = ffrag{0.f, 0.f, 0.f, 0.f};

    // ---- per-lane state: X dims {4q+r, 16+4q+r} of particle p ----
    float X[8];
    {
        const float* xp = x0 + (size_t)part * 32;
        float4 a = *(const float4*)(xp + 4 * q);
        float4 b = *(const float4*)(xp + 16 + 4 * q);
        X[0] = a.x; X[1] = a.y; X[2] = a.z; X[3] = a.w;
        X[4] = b.x; X[5] = b.y; X[6] = b.z; X[7] = b.w;
    }
    float V = v0[part];

    const float* nbase = noise + (size_t)part * 32;
    float4 nc0 = *(const float4*)(nbase + 4 * q);
    float4 nc1 = *(const float4*)(nbase + 16 + 4 * q);

    #pragma unroll 1
    for (int m = 0; m < MS; ++m) {
        const int mn = (m + 1 < MS) ? m + 1 : m;
        const float* np = nbase + (size_t)mn * ((size_t)NPART * 32);
        float4 nn0 = *(const float4*)(np + 4 * q);
        float4 nn1 = *(const float4*)(np + 16 + 4 * q);

        // B fragment: X -> packed bf16 (slot j = delta(q,j) by construction)
        int4 bxw = make_int4((int)pk2(X[0], X[1]), (int)pk2(X[2], X[3]),
                             (int)pk2(X[4], X[5]), (int)pk2(X[6], X[7]));
        bfrag BX = __builtin_bit_cast(bfrag, bxw);

        const float s = (float)m * dt;

        // ---- GEMM1: 8 independent MFMAs, C-init ready at step start ----
        ffrag C[8];
        #pragma unroll
        for (int mt = 0; mt < 8; ++mt) {
            ffrag c;
            #pragma unroll
            for (int r = 0; r < 4; ++r) c[r] = fmaf(s, W1s[mt][r], Stat[mt][r]);
            C[mt] = c;
        }
        #pragma unroll
        for (int mt = 0; mt < 8; ++mt)
            C[mt] = __builtin_amdgcn_mfma_f32_16x16x32_bf16(A1[mt], BX, C[mt], 0, 0, 0);

        // ---- tanh + pack: C-regs become GEMM2 B-fragments directly ----
        uint2 Hpk[8];
        #pragma unroll
        for (int mt = 0; mt < 8; ++mt) {
            const unsigned u0 = pk2(fast_tanh(C[mt][0]), fast_tanh(C[mt][1]));
            const unsigned u1 = pk2(fast_tanh(C[mt][2]), fast_tanh(C[mt][3]));
            Hpk[mt] = make_uint2(u0, u1);
        }

        // ---- GEMM2: Z = W2^T @ H, two 2-deep chains per N-tile ----
        ffrag D0a = Z0i, D0b = Zzero, D1a = Z1i, D1b = Zzero;
        #pragma unroll
        for (int kt = 0; kt < 4; ++kt) {
            int4 hw = make_int4((int)Hpk[2 * kt].x, (int)Hpk[2 * kt].y,
                                (int)Hpk[2 * kt + 1].x, (int)Hpk[2 * kt + 1].y);
            bfrag Hb = __builtin_bit_cast(bfrag, hw);
            if (kt & 1) {
                D0b = __builtin_amdgcn_mfma_f32_16x16x32_bf16(A2[0][kt], Hb, D0b, 0, 0, 0);
                D1b = __builtin_amdgcn_mfma_f32_16x16x32_bf16(A2[1][kt], Hb, D1b, 0, 0, 0);
            } else {
                D0a = __builtin_amdgcn_mfma_f32_16x16x32_bf16(A2[0][kt], Hb, D0a, 0, 0, 0);
                D1a = __builtin_amdgcn_mfma_f32_16x16x32_bf16(A2[1][kt], Hb, D1a, 0, 0, 0);
            }
        }
        ffrag D0 = D0a + D0b;   // Z[dim 4q+r][particle p]
        ffrag D1 = D1a + D1b;   // Z[dim 16+4q+r][particle p]

        float Z[8]  = {D0[0], D0[1], D0[2], D0[3], D1[0], D1[1], D1[2], D1[3]};
        float Nn[8] = {nc0.x, nc0.y, nc0.z, nc0.w, nc1.x, nc1.y, nc1.z, nc1.w};

        // V: (0.5-cr)*dt*sum(Z^2) + sqrt_dt*sum(Z*n); reduce across quads.
        float s2 = 0.0f, sn = 0.0f;
        #pragma unroll
        for (int j = 0; j < 8; ++j) {
            s2 = fmaf(Z[j], Z[j], s2);
            sn = fmaf(Z[j], Nn[j], sn);
        }
        s2 += __shfl_xor(s2, 16); s2 += __shfl_xor(s2, 32);
        sn += __shfl_xor(sn, 16); sn += __shfl_xor(sn, 32);
        V = fmaf(kv, s2, fmaf(sqrt_dt, sn, V));

        // X = ax*X - bcr*Z + sqrt_dt*n
        #pragma unroll
        for (int j = 0; j < 8; ++j) {
            float t = fmaf(-bcr, Z[j], sqrt_dt * Nn[j]);
            X[j] = fmaf(ax, X[j], t);
        }

        nc0 = nn0; nc1 = nn1;
    }

    // ---- store: dims {4q+r, 16+4q+r} of particle p; V on quad 0 ----
    float* xo = outX + (size_t)part * 32;
    *(float4*)(xo + 4 * q)      = make_float4(X[0], X[1], X[2], X[3]);
    *(float4*)(xo + 16 + 4 * q) = make_float4(X[4], X[5], X[6], X[7]);
    if (q == 0) outV[part] = V;
}

extern "C" void kernel_launch(void* const* d_in, const int* in_sizes, int n_in,
                              void* d_out, int out_size, void* d_ws, size_t ws_size,
                              hipStream_t stream) {
    const float* obs   = (const float*)d_in[0];
    const float* x0    = (const float*)d_in[1];
    const float* v0    = (const float*)d_in[2];
    const float* noise = (const float*)d_in[3];
    const float* W1    = (const float*)d_in[4];
    const float* b1    = (const float*)d_in[5];
    const float* W2    = (const float*)d_in[6];
    const float* b2    = (const float*)d_in[7];
    const float* th    = (const float*)d_in[8];
    const int*   oi    = (const int*)d_in[9];
    const int*   cr    = (const int*)d_in[10];

    float* outX = (float*)d_out;
    float* outV = outX + (size_t)NPART * 32;

    dim3 grid(NPART / 64);   // 512 blocks x 4 waves x 16 particles
    fused_sde_mfma<<<grid, BLOCK, 0, stream>>>(obs, x0, v0, noise, W1, b1, W2, b2,
                                               th, oi, cr, outX, outV);
}